// Round 1
// baseline (74.929 us; speedup 1.0000x reference)
//
#include <hip/hip_runtime.h>
#include <math.h>

// Problem constants (fixed by the reference)
constexpr int B_ROWS = 16384;
constexpr int D_COLS = 2048;
constexpr float EPS_F = 1e-8f;
constexpr int P_MAX = 512;     // partial-sum blocks for pass1

// ws float layout:
//  [0..3]                 group counts (float, atomic)
//  [16 .. 16+8192)        csum: group sums S_g, layout g*2048+col (atomic target)
//  [8224 .. 8224+P*8192)  per-block partials (float4-aligned)
constexpr int WS_CSUM = 16;
constexpr int WS_PART = 8224;   // byte offset 32896, 16B aligned

// ---------------------------------------------------------------------------
// pass1: per-block group sums in registers -> partials; atomic counts.
// 512 threads: thread t owns float4 column t (cols 4t..4t+3). One float4 per
// row per thread. g is block-uniform -> uniform switch (no divergence, no
// runtime-indexed register array).
// ---------------------------------------------------------------------------
__global__ __launch_bounds__(512) void pass1_partial_sums(
    const float* __restrict__ feat, const int* __restrict__ lab,
    const int* __restrict__ ses, float* __restrict__ ws, int P) {
  const int t = threadIdx.x;
  float4 a0 = {0.f, 0.f, 0.f, 0.f};
  float4 a1 = a0, a2 = a0, a3 = a0;
  int c0 = 0, c1 = 0, c2 = 0, c3 = 0;

  #pragma unroll 4
  for (int r = blockIdx.x; r < B_ROWS; r += P) {
    const int g = lab[r] * 2 + ses[r];             // block-uniform
    const float4 v = ((const float4*)(feat + (size_t)r * D_COLS))[t];
    switch (g) {
      case 0: a0.x += v.x; a0.y += v.y; a0.z += v.z; a0.w += v.w; c0++; break;
      case 1: a1.x += v.x; a1.y += v.y; a1.z += v.z; a1.w += v.w; c1++; break;
      case 2: a2.x += v.x; a2.y += v.y; a2.z += v.z; a2.w += v.w; c2++; break;
      default: a3.x += v.x; a3.y += v.y; a3.z += v.z; a3.w += v.w; c3++; break;
    }
  }

  float4* part = (float4*)(ws + WS_PART) + (size_t)blockIdx.x * 2048;
  part[t]          = a0;   // g0: float4 col t  -> floats g*2048 + 4t
  part[512 + t]    = a1;
  part[1024 + t]   = a2;
  part[1536 + t]   = a3;

  if (t == 0) {
    atomicAdd(ws + 0, (float)c0);
    atomicAdd(ws + 1, (float)c1);
    atomicAdd(ws + 2, (float)c2);
    atomicAdd(ws + 3, (float)c3);
  }
}

// ---------------------------------------------------------------------------
// pass2: reduce P partials -> csum. 32768 threads: (j4, chunk) with 16 chunks;
// each thread sums P/16 partials for one float4 column, then 4 atomic adds
// (16-way contention per address).
// ---------------------------------------------------------------------------
__global__ __launch_bounds__(256) void pass2_reduce(float* __restrict__ ws, int P) {
  const int tid = blockIdx.x * 256 + threadIdx.x;  // 0..32767
  const int j4 = tid & 2047;
  const int chunk = tid >> 11;                     // 0..15
  float4 s = {0.f, 0.f, 0.f, 0.f};
  const float4* part = (const float4*)(ws + WS_PART);
  for (int p = chunk; p < P; p += 16) {
    const float4 v = part[(size_t)p * 2048 + j4];
    s.x += v.x; s.y += v.y; s.z += v.z; s.w += v.w;
  }
  float* csum = ws + WS_CSUM + j4 * 4;
  atomicAdd(csum + 0, s.x);
  atomicAdd(csum + 1, s.y);
  atomicAdd(csum + 2, s.z);
  atomicAdd(csum + 3, s.w);
}

// ---------------------------------------------------------------------------
// pass3: final scalars from csum + counts.
//   center_loss = 1 - (sum_g ||S_g||)/B          (uses ||f_i|| = 1)
//   align/margin from pairwise dots of centers c_g = S_g/n_g (EPS clamp as ref)
// ---------------------------------------------------------------------------
__global__ __launch_bounds__(256) void pass3_finalize(
    const float* __restrict__ ws, float* __restrict__ out) {
  const int t = threadIdx.x;
  const float* S = ws + WS_CSUM;
  float n0 = 0, n1 = 0, n2 = 0, n3 = 0;
  float d01 = 0, d23 = 0, d02 = 0, d03 = 0, d12 = 0, d13 = 0;

  for (int col = t; col < D_COLS; col += 256) {
    const float s0 = S[col];
    const float s1 = S[2048 + col];
    const float s2 = S[4096 + col];
    const float s3 = S[6144 + col];
    n0 += s0 * s0; n1 += s1 * s1; n2 += s2 * s2; n3 += s3 * s3;
    d01 += s0 * s1; d23 += s2 * s3;
    d02 += s0 * s2; d03 += s0 * s3; d12 += s1 * s2; d13 += s1 * s3;
  }

  // wave64 butterfly reduce for all 10 accumulators
  #pragma unroll
  for (int m = 32; m >= 1; m >>= 1) {
    n0  += __shfl_xor(n0, m, 64);  n1  += __shfl_xor(n1, m, 64);
    n2  += __shfl_xor(n2, m, 64);  n3  += __shfl_xor(n3, m, 64);
    d01 += __shfl_xor(d01, m, 64); d23 += __shfl_xor(d23, m, 64);
    d02 += __shfl_xor(d02, m, 64); d03 += __shfl_xor(d03, m, 64);
    d12 += __shfl_xor(d12, m, 64); d13 += __shfl_xor(d13, m, 64);
  }

  __shared__ float red[4][10];
  const int wv = t >> 6, ln = t & 63;
  if (ln == 0) {
    red[wv][0] = n0;  red[wv][1] = n1;  red[wv][2] = n2;  red[wv][3] = n3;
    red[wv][4] = d01; red[wv][5] = d23; red[wv][6] = d02; red[wv][7] = d03;
    red[wv][8] = d12; red[wv][9] = d13;
  }
  __syncthreads();

  if (t == 0) {
    float v[10];
    #pragma unroll
    for (int k = 0; k < 10; ++k)
      v[k] = red[0][k] + red[1][k] + red[2][k] + red[3][k];

    const float NS0 = sqrtf(v[0]), NS1 = sqrtf(v[1]);
    const float NS2 = sqrtf(v[2]), NS3 = sqrtf(v[3]);
    const float cn0 = ws[0], cn1 = ws[1], cn2 = ws[2], cn3 = ws[3];
    // center norms ||c_g|| = ||S_g|| / n_g
    const float N0 = NS0 / cn0, N1 = NS1 / cn1;
    const float N2 = NS2 / cn2, N3 = NS3 / cn3;

    // cos(c_a, c_b) = (S_a.S_b/(n_a n_b)) / max(||c_a||*||c_b||, EPS)
    const float c01 = (v[4] / (cn0 * cn1)) / fmaxf(N0 * N1, EPS_F);
    const float c23 = (v[5] / (cn2 * cn3)) / fmaxf(N2 * N3, EPS_F);
    const float c02 = (v[6] / (cn0 * cn2)) / fmaxf(N0 * N2, EPS_F);
    const float c03 = (v[7] / (cn0 * cn3)) / fmaxf(N0 * N3, EPS_F);
    const float c12 = (v[8] / (cn1 * cn2)) / fmaxf(N1 * N2, EPS_F);
    const float c13 = (v[9] / (cn1 * cn3)) / fmaxf(N1 * N3, EPS_F);

    const float center_loss = 1.0f - (NS0 + NS1 + NS2 + NS3) * (1.0f / (float)B_ROWS);
    const float align_loss = ((1.0f - c01) + (1.0f - c23)) * 0.5f;
    const float margin_loss = (c02 + c03 + c12 + c13) * 0.25f;

    out[0] = center_loss + 0.1f * align_loss + 0.05f * margin_loss;
    out[1] = center_loss;
    out[2] = align_loss;
    out[3] = margin_loss;
  }
}

extern "C" void kernel_launch(void* const* d_in, const int* in_sizes, int n_in,
                              void* d_out, int out_size, void* d_ws, size_t ws_size,
                              hipStream_t stream) {
  const float* feat = (const float*)d_in[0];
  const int* lab = (const int*)d_in[1];
  const int* ses = (const int*)d_in[2];
  float* ws = (float*)d_ws;
  float* out = (float*)d_out;

  int P = P_MAX;
  {
    const size_t need = ((size_t)WS_PART + (size_t)P * 8192) * 4;
    if (ws_size < need) {
      size_t cap = (ws_size / 4 > (size_t)WS_PART)
                       ? (ws_size / 4 - (size_t)WS_PART) / 8192
                       : 0;
      P = (int)cap;
      if (P < 1) P = 1;
      if (P > P_MAX) P = P_MAX;
    }
  }

  // zero counts + csum (re-runs on every graph replay)
  hipMemsetAsync(ws, 0, (size_t)(WS_CSUM + 8192) * sizeof(float), stream);

  hipLaunchKernelGGL(pass1_partial_sums, dim3(P), dim3(512), 0, stream,
                     feat, lab, ses, ws, P);
  hipLaunchKernelGGL(pass2_reduce, dim3(128), dim3(256), 0, stream, ws, P);
  hipLaunchKernelGGL(pass3_finalize, dim3(1), dim3(256), 0, stream, ws, out);
}

// Round 2
// 46.528 us; speedup vs baseline: 1.6104x; 1.6104x over previous
//
#include <hip/hip_runtime.h>
#include <math.h>

// Problem constants (fixed by the reference)
constexpr int B_ROWS = 16384;
constexpr int D_COLS = 2048;
constexpr float EPS_F = 1e-8f;
constexpr int P_MAX = 512;     // partial-sum blocks for pass1

// ws float layout (no zero-init needed anywhere: every location is written
// by a plain store before it is read):
//  [0 .. 4*P)             per-block counts, float4 per block {c0,c1,c2,c3}
//  [2048 .. 2048+8192)    csum: group sums S_g, g*2048+col (pass2 stores)
//  [16384 .. +P*8192)     per-block partials (float4-aligned)
constexpr int WS_CSUM = 2048;
constexpr int WS_PART = 16384;  // byte offset 65536, 16B aligned

// ---------------------------------------------------------------------------
// pass1: per-block group sums in registers -> partials; counts via plain
// float4 store (no atomics). 512 threads: thread t owns float4 column t.
// g is block-uniform (r depends only on blockIdx) -> scalar loads, no
// divergence, no runtime-indexed register arrays.
// ---------------------------------------------------------------------------
__global__ __launch_bounds__(512) void pass1_partial_sums(
    const float* __restrict__ feat, const int* __restrict__ lab,
    const int* __restrict__ ses, float* __restrict__ ws, int P) {
  const int t = threadIdx.x;
  float4 a0 = {0.f, 0.f, 0.f, 0.f};
  float4 a1 = a0, a2 = a0, a3 = a0;
  int c0 = 0, c1 = 0, c2 = 0, c3 = 0;

  #pragma unroll 4
  for (int r = blockIdx.x; r < B_ROWS; r += P) {
    const int g = lab[r] * 2 + ses[r];             // block-uniform
    const float4 v = ((const float4*)(feat + (size_t)r * D_COLS))[t];
    switch (g) {
      case 0: a0.x += v.x; a0.y += v.y; a0.z += v.z; a0.w += v.w; c0++; break;
      case 1: a1.x += v.x; a1.y += v.y; a1.z += v.z; a1.w += v.w; c1++; break;
      case 2: a2.x += v.x; a2.y += v.y; a2.z += v.z; a2.w += v.w; c2++; break;
      default: a3.x += v.x; a3.y += v.y; a3.z += v.z; a3.w += v.w; c3++; break;
    }
  }

  float4* part = (float4*)(ws + WS_PART) + (size_t)blockIdx.x * 2048;
  part[t]          = a0;   // g0: float4 col t  -> floats g*2048 + 4t
  part[512 + t]    = a1;
  part[1024 + t]   = a2;
  part[1536 + t]   = a3;

  if (t == 0) {
    float4 cnt = {(float)c0, (float)c1, (float)c2, (float)c3};
    ((float4*)ws)[blockIdx.x] = cnt;               // plain store, no atomic
  }
}

// ---------------------------------------------------------------------------
// pass2: reduce P partials -> csum with NO atomics. 128 blocks x 256 threads.
// Block b owns 16 float4 columns (j4 = b*16 + (t&15)); thread's chunk =
// t>>4 handles p = chunk, chunk+16, ... Then LDS reduce 16 chunks -> 1 and
// plain-store the final float4.
// ---------------------------------------------------------------------------
__global__ __launch_bounds__(256) void pass2_reduce(float* __restrict__ ws, int P) {
  const int t = threadIdx.x;
  const int jloc = t & 15;                 // column within block
  const int chunk = t >> 4;                // 0..15
  const int j4 = blockIdx.x * 16 + jloc;   // 0..2047 (csum float4 index)

  float4 s = {0.f, 0.f, 0.f, 0.f};
  const float4* part = (const float4*)(ws + WS_PART);
  for (int p = chunk; p < P; p += 16) {
    const float4 v = part[(size_t)p * 2048 + j4];
    s.x += v.x; s.y += v.y; s.z += v.z; s.w += v.w;
  }

  __shared__ float4 lds[256];
  lds[t] = s;
  __syncthreads();

  if (t < 16) {
    float4 acc = lds[t];
    #pragma unroll
    for (int c = 1; c < 16; ++c) {
      const float4 v = lds[c * 16 + t];
      acc.x += v.x; acc.y += v.y; acc.z += v.z; acc.w += v.w;
    }
    ((float4*)(ws + WS_CSUM))[blockIdx.x * 16 + t] = acc;
  }
}

// ---------------------------------------------------------------------------
// pass3: final scalars from csum + count partials.
//   center_loss = 1 - (sum_g ||S_g||)/B          (uses ||f_i|| = 1)
//   align/margin from pairwise dots of centers c_g = S_g/n_g (EPS clamp as ref)
// ---------------------------------------------------------------------------
__global__ __launch_bounds__(256) void pass3_finalize(
    const float* __restrict__ ws, float* __restrict__ out, int P) {
  const int t = threadIdx.x;
  const float* S = ws + WS_CSUM;
  float n0 = 0, n1 = 0, n2 = 0, n3 = 0;
  float d01 = 0, d23 = 0, d02 = 0, d03 = 0, d12 = 0, d13 = 0;
  float k0 = 0, k1 = 0, k2 = 0, k3 = 0;    // group counts

  for (int col = t; col < D_COLS; col += 256) {
    const float s0 = S[col];
    const float s1 = S[2048 + col];
    const float s2 = S[4096 + col];
    const float s3 = S[6144 + col];
    n0 += s0 * s0; n1 += s1 * s1; n2 += s2 * s2; n3 += s3 * s3;
    d01 += s0 * s1; d23 += s2 * s3;
    d02 += s0 * s2; d03 += s0 * s3; d12 += s1 * s2; d13 += s1 * s3;
  }
  for (int p = t; p < P; p += 256) {
    const float4 c = ((const float4*)ws)[p];
    k0 += c.x; k1 += c.y; k2 += c.z; k3 += c.w;
  }

  // wave64 butterfly reduce for all 14 accumulators
  #pragma unroll
  for (int m = 32; m >= 1; m >>= 1) {
    n0  += __shfl_xor(n0, m, 64);  n1  += __shfl_xor(n1, m, 64);
    n2  += __shfl_xor(n2, m, 64);  n3  += __shfl_xor(n3, m, 64);
    d01 += __shfl_xor(d01, m, 64); d23 += __shfl_xor(d23, m, 64);
    d02 += __shfl_xor(d02, m, 64); d03 += __shfl_xor(d03, m, 64);
    d12 += __shfl_xor(d12, m, 64); d13 += __shfl_xor(d13, m, 64);
    k0  += __shfl_xor(k0, m, 64);  k1  += __shfl_xor(k1, m, 64);
    k2  += __shfl_xor(k2, m, 64);  k3  += __shfl_xor(k3, m, 64);
  }

  __shared__ float red[4][14];
  const int wv = t >> 6, ln = t & 63;
  if (ln == 0) {
    red[wv][0] = n0;  red[wv][1] = n1;  red[wv][2] = n2;  red[wv][3] = n3;
    red[wv][4] = d01; red[wv][5] = d23; red[wv][6] = d02; red[wv][7] = d03;
    red[wv][8] = d12; red[wv][9] = d13;
    red[wv][10] = k0; red[wv][11] = k1; red[wv][12] = k2; red[wv][13] = k3;
  }
  __syncthreads();

  if (t == 0) {
    float v[14];
    #pragma unroll
    for (int k = 0; k < 14; ++k)
      v[k] = red[0][k] + red[1][k] + red[2][k] + red[3][k];

    const float NS0 = sqrtf(v[0]), NS1 = sqrtf(v[1]);
    const float NS2 = sqrtf(v[2]), NS3 = sqrtf(v[3]);
    const float cn0 = v[10], cn1 = v[11], cn2 = v[12], cn3 = v[13];
    // center norms ||c_g|| = ||S_g|| / n_g
    const float N0 = NS0 / cn0, N1 = NS1 / cn1;
    const float N2 = NS2 / cn2, N3 = NS3 / cn3;

    // cos(c_a, c_b) = (S_a.S_b/(n_a n_b)) / max(||c_a||*||c_b||, EPS)
    const float c01 = (v[4] / (cn0 * cn1)) / fmaxf(N0 * N1, EPS_F);
    const float c23 = (v[5] / (cn2 * cn3)) / fmaxf(N2 * N3, EPS_F);
    const float c02 = (v[6] / (cn0 * cn2)) / fmaxf(N0 * N2, EPS_F);
    const float c03 = (v[7] / (cn0 * cn3)) / fmaxf(N0 * N3, EPS_F);
    const float c12 = (v[8] / (cn1 * cn2)) / fmaxf(N1 * N2, EPS_F);
    const float c13 = (v[9] / (cn1 * cn3)) / fmaxf(N1 * N3, EPS_F);

    const float center_loss = 1.0f - (NS0 + NS1 + NS2 + NS3) * (1.0f / (float)B_ROWS);
    const float align_loss = ((1.0f - c01) + (1.0f - c23)) * 0.5f;
    const float margin_loss = (c02 + c03 + c12 + c13) * 0.25f;

    out[0] = center_loss + 0.1f * align_loss + 0.05f * margin_loss;
    out[1] = center_loss;
    out[2] = align_loss;
    out[3] = margin_loss;
  }
}

extern "C" void kernel_launch(void* const* d_in, const int* in_sizes, int n_in,
                              void* d_out, int out_size, void* d_ws, size_t ws_size,
                              hipStream_t stream) {
  const float* feat = (const float*)d_in[0];
  const int* lab = (const int*)d_in[1];
  const int* ses = (const int*)d_in[2];
  float* ws = (float*)d_ws;
  float* out = (float*)d_out;

  int P = P_MAX;
  {
    const size_t need = ((size_t)WS_PART + (size_t)P * 8192) * 4;
    if (ws_size < need) {
      size_t cap = (ws_size / 4 > (size_t)WS_PART)
                       ? (ws_size / 4 - (size_t)WS_PART) / 8192
                       : 0;
      P = (int)cap;
      if (P < 1) P = 1;
      if (P > P_MAX) P = P_MAX;
    }
  }

  // NO memset: every ws location is plain-stored before it is read.
  hipLaunchKernelGGL(pass1_partial_sums, dim3(P), dim3(512), 0, stream,
                     feat, lab, ses, ws, P);
  hipLaunchKernelGGL(pass2_reduce, dim3(128), dim3(256), 0, stream, ws, P);
  hipLaunchKernelGGL(pass3_finalize, dim3(1), dim3(256), 0, stream, ws, out, P);
}